// Round 4
// baseline (60.221 us; speedup 1.0000x reference)
//
#include <hip/hip_runtime.h>

// Problem constants (fixed by setup_inputs): B=16, T=1024, D=256, SCALE=8 -> N=128
constexpr int B = 16;
constexpr int T = 1024;
constexpr int D = 256;
constexpr int N = 128;      // T / SCALE
constexpr int D4 = D / 4;   // 64 float4 per row
constexpr float NEG_INF_V = -1e30f;

// clang-native vector types (HIP_vector_type is rejected by nontemporal builtins)
using f32x4 = float __attribute__((ext_vector_type(4)));
using f32x2 = float __attribute__((ext_vector_type(2)));

__device__ __forceinline__ f32x4 max4(f32x4 a, f32x4 b) {
    f32x4 r;
    r.x = fmaxf(a.x, b.x); r.y = fmaxf(a.y, b.y);
    r.z = fmaxf(a.z, b.z); r.w = fmaxf(a.w, b.w);
    return r;
}

// Kernel P: pooled[b][n][:] = max over 8 frames of (feats + (1-mask)*NEG_INF),
//           smask[b*N+n]   = max over 8 frames of mask  (lane 0 only, free).
// grid: B*N/4 = 512 blocks x 256 threads; one 64-lane wave per pooled row n.
// feats is read-once -> nontemporal loads; pooled/smask reused next kernel -> cached.
__global__ __launch_bounds__(256) void pool_feats_kernel(const f32x4* __restrict__ feats,
                                                         const float* __restrict__ mask,
                                                         f32x4* __restrict__ pooled,
                                                         float* __restrict__ smask) {
    int tid = threadIdx.x;
    int nloc = tid >> 6;                // 0..3
    int lane = tid & 63;                // float4 index over D
    int gidx = blockIdx.x * 4 + nloc;   // b*N + n
    int b = gidx >> 7;
    int n = gidx & (N - 1);
    const float* mrow = mask + (size_t)b * T + (size_t)n * 8;
    const f32x4* frow = feats + ((size_t)b * T + (size_t)n * 8) * D4 + lane;
    f32x4 acc = (f32x4)(-INFINITY);
    float mmax = -INFINITY;
#pragma unroll
    for (int t = 0; t < 8; ++t) {
        float m = mrow[t];              // wave-uniform address -> broadcast
        mmax = fmaxf(mmax, m);
        float add = (1.0f - m) * NEG_INF_V;
        f32x4 v = __builtin_nontemporal_load(&frow[(size_t)t * D4]);
        acc = max4(acc, v + (f32x4)add);
    }
    pooled[(size_t)gidx * D4 + lane] = acc;
    if (lane == 0) smask[gidx] = mmax;
}

// Kernel F: everything else. One block per (b,s), 4 waves x 64 lanes.
//  - issue all 16 band-row pooled loads up front (independent, in flight during stores)
//  - zero region: wave w writes contiguous rows [w*32, w*32+32) minus band rows (nt)
//  - band rows: static prefix-max chain in registers, wave-uniform select by w (nt)
//  - meta (threads 0..127): mask2d row + bounds row (length via wave shfl-reduce)
__global__ __launch_bounds__(256) void fill_all_kernel(const f32x4* __restrict__ pooled,
                                                       const float* __restrict__ smask,
                                                       const f32x4* __restrict__ mask4,
                                                       f32x4* __restrict__ out,
                                                       f32x2* __restrict__ bounds,
                                                       float* __restrict__ m2d) {
    int blk = blockIdx.x;              // b*N + s
    int b = blk >> 7;
    int s = blk & (N - 1);
    int w = threadIdx.x >> 6;          // wave id 0..3
    int lane = threadIdx.x & 63;       // float4 index over D

    const f32x4 zero = (f32x4)0.f;
    const f32x4 ninf = (f32x4)(-INFINITY);
    f32x4* orow = out + ((size_t)blk * N) * D4 + lane;   // + e*D4

    // Issue all 16 band-row loads up front (static indices -> registers).
    const f32x4* prow = pooled + ((size_t)b * N) * D4 + lane;
    f32x4 pr[16];
#pragma unroll
    for (int k = 0; k < 16; ++k) {
        int e = s + k;
        pr[k] = (e < N) ? prow[(size_t)e * D4] : ninf;   // wave-uniform predicate
    }

    // Zero region: contiguous 32-row chunk per wave (32 KB sequential nt stream).
    int band_hi = s + 15;
    int e0 = w * 32;
#pragma unroll 4
    for (int e = e0; e < e0 + 32; ++e) {
        if (e >= s && e <= band_hi) continue;            // band written below
        __builtin_nontemporal_store(zero, &orow[(size_t)e * D4]);
    }

    // Static prefix-max chain: pr[k] becomes max(pooled[s..s+k]).
#pragma unroll
    for (int k = 1; k < 16; ++k) pr[k] = max4(pr[k - 1], pr[k]);

    // Wave w owns offsets w, w+4, w+8, w+12 (uniform branch -> static reg indices).
    f32x4 r0, r1, r2, r3;
    if (w == 0)      { r0 = pr[0]; r1 = pr[4]; r2 = pr[8];  r3 = pr[12]; }
    else if (w == 1) { r0 = pr[1]; r1 = pr[5]; r2 = pr[9];  r3 = pr[13]; }
    else if (w == 2) { r0 = pr[2]; r1 = pr[6]; r2 = pr[10]; r3 = pr[14]; }
    else             { r0 = pr[3]; r1 = pr[7]; r2 = pr[11]; r3 = pr[15]; }

    const float* sm = smask + b * N;
#pragma unroll
    for (int t = 0; t < 4; ++t) {
        int e_t = s + w + 4 * t;
        f32x4 r = (t == 0) ? r0 : (t == 1) ? r1 : (t == 2) ? r2 : r3;
        if (e_t < N) {
            float m = sm[e_t];
            __builtin_nontemporal_store(r * (f32x4)m, &orow[(size_t)e_t * D4]);
        }
    }

    // Meta: threads 0..127 (waves 0 and 1). Each wave reduces the mask row for length.
    if (threadIdx.x < 128) {
        int e = threadIdx.x;
        const f32x4* mr = mask4 + (size_t)b * (T / 4);   // 256 float4 per batch
        float sum = 0.0f;
        for (int i = lane; i < T / 4; i += 64) {
            f32x4 v = mr[i];
            sum += v.x + v.y + v.z + v.w;
        }
#pragma unroll
        for (int d = 32; d > 0; d >>= 1) sum += __shfl_xor(sum, d, 64);
        int len1 = (int)sum - 1;

        float m = (e >= s && e <= band_hi) ? sm[e] : 0.0f;
        __builtin_nontemporal_store(m, &m2d[(size_t)blk * N + e]);
        int im = (int)m;
        int b0 = min(s * 8, len1) * im;
        int b1 = min(e * 8 + 7, len1) * im;
        f32x2 bv; bv.x = (float)b0; bv.y = (float)b1;
        __builtin_nontemporal_store(bv, &bounds[(size_t)blk * N + e]);
    }
}

extern "C" void kernel_launch(void* const* d_in, const int* in_sizes, int n_in,
                              void* d_out, int out_size, void* d_ws, size_t ws_size,
                              hipStream_t stream) {
    const float* feats = (const float*)d_in[0];   // [B,T,D]
    const float* mask  = (const float*)d_in[1];   // [B,T]
    float* out = (float*)d_out;

    // workspace: pooled (B*N*D floats = 2 MB), smask (B*N floats)
    float* pooled = (float*)d_ws;
    float* smask  = pooled + (size_t)B * N * D;

    hipLaunchKernelGGL(pool_feats_kernel, dim3(B * N / 4), dim3(256), 0, stream,
                       (const f32x4*)feats, mask, (f32x4*)pooled, smask);

    float* bounds = out + (size_t)B * N * N * D;
    float* m2d    = bounds + (size_t)B * N * N * 2;
    hipLaunchKernelGGL(fill_all_kernel, dim3(B * N), dim3(256), 0, stream,
                       (const f32x4*)pooled, smask, (const f32x4*)mask,
                       (f32x4*)out, (f32x2*)bounds, m2d);
}